// Round 1
// baseline (1032.282 us; speedup 1.0000x reference)
//
#include <hip/hip_runtime.h>
#include <math.h>

// ---------------------------------------------------------------------------
// TopoPoolNet: GCN(128->64) -> GCN(64->64) -> sigmoid score gate ->
//              per-graph max||mean pool -> MLP(128->64->2)
// Strategy: build CSR-by-destination once (counts, scan, cursor scatter of
// {row,norm} packs), then each GCN layer is an atomics-free gather-aggregate
// with one wave per node (lane == feature, H==64).
// ---------------------------------------------------------------------------

#define TPN_BLK 256

// ---- deg counting: degw[c] += w, cnt[c] += 1 -------------------------------
__global__ void tpn_count(const int* __restrict__ ei, const float* __restrict__ ew,
                          float* __restrict__ degw, int* __restrict__ cnt, int E) {
    int e = blockIdx.x * blockDim.x + threadIdx.x;
    if (e >= E) return;
    int c = ei[E + e];
    atomicAdd(&degw[c], ew[e]);
    atomicAdd(&cnt[c], 1);
}

// ---- dis[i] = deg>0 ? rsqrt(max(deg,1e-12)) : 0 ----------------------------
__global__ void tpn_dis(const float* __restrict__ degw, float* __restrict__ dis, int N) {
    int i = blockIdx.x * blockDim.x + threadIdx.x;
    if (i >= N) return;
    float d = degw[i];
    dis[i] = (d > 0.0f) ? rsqrtf(fmaxf(d, 1e-12f)) : 0.0f;
}

// ---- scan step 1: per-block (1024 elems) sums ------------------------------
__global__ void tpn_scan1(const int* __restrict__ cnt, int* __restrict__ bsum, int N) {
    __shared__ int sh[TPN_BLK];
    int base = blockIdx.x * 1024 + threadIdx.x * 4;
    int s = 0;
    #pragma unroll
    for (int j = 0; j < 4; ++j) { int i = base + j; if (i < N) s += cnt[i]; }
    sh[threadIdx.x] = s; __syncthreads();
    for (int st = TPN_BLK / 2; st > 0; st >>= 1) {
        if (threadIdx.x < st) sh[threadIdx.x] += sh[threadIdx.x + st];
        __syncthreads();
    }
    if (threadIdx.x == 0) bsum[blockIdx.x] = sh[0];
}

// ---- scan step 2: serial exclusive scan of block sums (nb ~ 98) ------------
__global__ void tpn_scan2(int* __restrict__ bsum, int nb) {
    if (blockIdx.x == 0 && threadIdx.x == 0) {
        int acc = 0;
        for (int b = 0; b < nb; ++b) { int v = bsum[b]; bsum[b] = acc; acc += v; }
    }
}

// ---- scan step 3: exclusive scan within block + block offset ---------------
__global__ void tpn_scan3(const int* __restrict__ cnt, const int* __restrict__ bsum,
                          int* __restrict__ off, int* __restrict__ cur, int N) {
    __shared__ int sh[TPN_BLK];
    int base = blockIdx.x * 1024 + threadIdx.x * 4;
    int local[4]; int s = 0;
    #pragma unroll
    for (int j = 0; j < 4; ++j) {
        int i = base + j; int v = (i < N) ? cnt[i] : 0;
        local[j] = s; s += v;
    }
    sh[threadIdx.x] = s; __syncthreads();
    // Hillis-Steele inclusive scan over thread sums
    for (int st = 1; st < TPN_BLK; st <<= 1) {
        int v = (threadIdx.x >= st) ? sh[threadIdx.x - st] : 0;
        __syncthreads();
        sh[threadIdx.x] += v;
        __syncthreads();
    }
    int pre = ((threadIdx.x > 0) ? sh[threadIdx.x - 1] : 0) + bsum[blockIdx.x];
    #pragma unroll
    for (int j = 0; j < 4; ++j) {
        int i = base + j;
        if (i < N) { int o = pre + local[j]; off[i] = o; cur[i] = o; }
    }
}

// ---- bucket edges by col: packed[pos] = {row, norm} ------------------------
__global__ void tpn_edges(const int* __restrict__ ei, const float* __restrict__ ew,
                          const float* __restrict__ dis, int* __restrict__ cur,
                          uint2* __restrict__ packed, int E) {
    int e = blockIdx.x * blockDim.x + threadIdx.x;
    if (e >= E) return;
    int r = ei[e], c = ei[E + e];
    float nv = dis[r] * ew[e] * dis[c];
    int p = atomicAdd(&cur[c], 1);
    packed[p] = make_uint2((unsigned)r, __float_as_uint(nv));
}

// ---- dense GEMM: Y[n, f] = sum_k X[n,k] * W[k,f];  one wave/node, lane=f ---
__global__ void tpn_gemm(const float* __restrict__ X, const float* __restrict__ W,
                         float* __restrict__ Y, int N, int K) {
    int wid = (blockIdx.x * blockDim.x + threadIdx.x) >> 6;
    int lane = threadIdx.x & 63;
    if (wid >= N) return;
    const float* xr = X + (size_t)wid * K;
    float acc = 0.0f;
    for (int k = 0; k < K; k += 4) {
        float4 xv = *reinterpret_cast<const float4*>(xr + k);
        acc = fmaf(xv.x, W[(k + 0) * 64 + lane], acc);
        acc = fmaf(xv.y, W[(k + 1) * 64 + lane], acc);
        acc = fmaf(xv.z, W[(k + 2) * 64 + lane], acc);
        acc = fmaf(xv.w, W[(k + 3) * 64 + lane], acc);
    }
    Y[(size_t)wid * 64 + lane] = acc;
}

// ---- aggregate: Hout[n,:] = relu(sum_{e in in(n)} norm_e * Hin[row_e,:] + b)
//      optionally fused sigmoid score gate (layer 2) ------------------------
template <bool FUSE_SCORE>
__global__ void tpn_agg(const uint2* __restrict__ packed, const int* __restrict__ off,
                        const int* __restrict__ cnt, const float* __restrict__ Hin,
                        const float* __restrict__ bias, const float* __restrict__ pw,
                        const float* __restrict__ pb, float* __restrict__ Hout, int N) {
    int wid = (blockIdx.x * blockDim.x + threadIdx.x) >> 6;
    int lane = threadIdx.x & 63;
    if (wid >= N) return;
    int start = off[wid], n = cnt[wid];
    float acc = 0.0f;
    int j = 0;
    for (; j + 3 < n; j += 4) {
        uint2 p0 = packed[start + j + 0];
        uint2 p1 = packed[start + j + 1];
        uint2 p2 = packed[start + j + 2];
        uint2 p3 = packed[start + j + 3];
        acc = fmaf(__uint_as_float(p0.y), Hin[(size_t)p0.x * 64 + lane], acc);
        acc = fmaf(__uint_as_float(p1.y), Hin[(size_t)p1.x * 64 + lane], acc);
        acc = fmaf(__uint_as_float(p2.y), Hin[(size_t)p2.x * 64 + lane], acc);
        acc = fmaf(__uint_as_float(p3.y), Hin[(size_t)p3.x * 64 + lane], acc);
    }
    for (; j < n; ++j) {
        uint2 p = packed[start + j];
        acc = fmaf(__uint_as_float(p.y), Hin[(size_t)p.x * 64 + lane], acc);
    }
    float h = fmaxf(acc + bias[lane], 0.0f);
    if (FUSE_SCORE) {
        float t = h * pw[lane];
        #pragma unroll
        for (int m = 32; m > 0; m >>= 1) t += __shfl_xor(t, m);
        float s = 1.0f / (1.0f + expf(-(t + pb[0])));
        h *= s;
    }
    Hout[(size_t)wid * 64 + lane] = h;
}

// ---- per-graph max || mean pooling (batch sorted) --------------------------
__global__ void tpn_pool(const float* __restrict__ Hs, const int* __restrict__ batch,
                         int N, float* __restrict__ Gf) {
    int g = blockIdx.x;
    // lower_bound(batch, g) and lower_bound(batch, g+1)
    int s, e;
    {
        int lo = 0, hi = N;
        while (lo < hi) { int mid = (lo + hi) >> 1; if (batch[mid] < g) lo = mid + 1; else hi = mid; }
        s = lo;
        lo = 0; hi = N;
        while (lo < hi) { int mid = (lo + hi) >> 1; if (batch[mid] < g + 1) lo = mid + 1; else hi = mid; }
        e = lo;
    }
    int lane = threadIdx.x & 63;
    int w = threadIdx.x >> 6;  // 0..3
    float mx = -3.4e38f, sm = 0.0f;
    for (int i = s + w; i < e; i += 4) {
        float v = Hs[(size_t)i * 64 + lane];
        mx = fmaxf(mx, v);
        sm += v;
    }
    __shared__ float shm[4][64], shs[4][64];
    shm[w][lane] = mx; shs[w][lane] = sm;
    __syncthreads();
    if (w == 0) {
        mx = fmaxf(fmaxf(shm[0][lane], shm[1][lane]), fmaxf(shm[2][lane], shm[3][lane]));
        sm = shs[0][lane] + shs[1][lane] + shs[2][lane] + shs[3][lane];
        float c = (float)(e - s);
        float inv = 1.0f / fmaxf(c, 1.0f);
        Gf[g * 128 + lane]      = mx;
        Gf[g * 128 + 64 + lane] = sm * inv;
    }
}

// ---- final MLP: out = relu(G @ lw1 + lb1) @ lw2 + lb2 ----------------------
__global__ void tpn_mlp(const float* __restrict__ Gf, const float* __restrict__ lw1,
                        const float* __restrict__ lb1, const float* __restrict__ lw2,
                        const float* __restrict__ lb2, float* __restrict__ out,
                        int G, int C) {
    int wid = (blockIdx.x * blockDim.x + threadIdx.x) >> 6;
    int lane = threadIdx.x & 63;
    if (wid >= G) return;
    const float* gr = Gf + (size_t)wid * 128;
    float acc = lb1[lane];
    for (int k = 0; k < 128; k += 4) {
        float4 gv = *reinterpret_cast<const float4*>(gr + k);
        acc = fmaf(gv.x, lw1[(k + 0) * 64 + lane], acc);
        acc = fmaf(gv.y, lw1[(k + 1) * 64 + lane], acc);
        acc = fmaf(gv.z, lw1[(k + 2) * 64 + lane], acc);
        acc = fmaf(gv.w, lw1[(k + 3) * 64 + lane], acc);
    }
    float t = fmaxf(acc, 0.0f);
    for (int c = 0; c < C; ++c) {
        float v = t * lw2[lane * C + c];
        #pragma unroll
        for (int m = 32; m > 0; m >>= 1) v += __shfl_xor(v, m);
        if (lane == 0) out[wid * C + c] = v + lb2[c];
    }
}

// ---------------------------------------------------------------------------
extern "C" void kernel_launch(void* const* d_in, const int* in_sizes, int n_in,
                              void* d_out, int out_size, void* d_ws, size_t ws_size,
                              hipStream_t stream) {
    const float* x   = (const float*)d_in[0];
    const int*   ei  = (const int*)  d_in[1];
    const float* ew  = (const float*)d_in[2];
    const int*   bat = (const int*)  d_in[3];
    const float* W1  = (const float*)d_in[5];
    const float* b1  = (const float*)d_in[6];
    const float* W2  = (const float*)d_in[7];
    const float* b2  = (const float*)d_in[8];
    const float* pw  = (const float*)d_in[9];
    const float* pb  = (const float*)d_in[10];
    const float* lw1 = (const float*)d_in[11];
    const float* lb1 = (const float*)d_in[12];
    const float* lw2 = (const float*)d_in[13];
    const float* lb2 = (const float*)d_in[14];
    float* out = (float*)d_out;

    const int N  = in_sizes[3];
    const int E  = in_sizes[2];
    const int IN = in_sizes[0] / N;   // 128
    const int C  = in_sizes[14];      // 2
    const int G  = out_size / C;      // 128

    // ---- workspace layout (all 256B-aligned) ----
    char* ws = (char*)d_ws;
    size_t o = 0;
    auto alloc = [&](size_t bytes) { void* p = ws + o; o = (o + bytes + 255) & ~(size_t)255; return p; };
    float* degw   = (float*)alloc((size_t)N * 4);
    int*   cnt    = (int*)  alloc((size_t)N * 4);
    float* dis    = (float*)alloc((size_t)N * 4);
    int*   off    = (int*)  alloc((size_t)N * 4);
    int*   cur    = (int*)  alloc((size_t)N * 4);
    const int nb  = (N + 1023) / 1024;
    int*   bsum   = (int*)  alloc((size_t)nb * 4);
    uint2* packed = (uint2*)alloc((size_t)E * 8);
    float* hA     = (float*)alloc((size_t)N * 64 * 4);
    float* hB     = (float*)alloc((size_t)N * 64 * 4);
    float* Gf     = (float*)alloc((size_t)G * 128 * 4);
    (void)ws_size; (void)n_in;

    // zero degw + cnt (adjacent regions)
    hipMemsetAsync(degw, 0, (size_t)2 * N * 4 + 256, stream);

    const int eb = (E + TPN_BLK - 1) / TPN_BLK;
    const int nbx = (N + TPN_BLK - 1) / TPN_BLK;

    tpn_count<<<eb, TPN_BLK, 0, stream>>>(ei, ew, degw, cnt, E);
    tpn_dis<<<nbx, TPN_BLK, 0, stream>>>(degw, dis, N);
    tpn_scan1<<<nb, TPN_BLK, 0, stream>>>(cnt, bsum, N);
    tpn_scan2<<<1, 64, 0, stream>>>(bsum, nb);
    tpn_scan3<<<nb, TPN_BLK, 0, stream>>>(cnt, bsum, off, cur, N);
    tpn_edges<<<eb, TPN_BLK, 0, stream>>>(ei, ew, dis, cur, packed, E);

    const int wgrid = (N * 64 + TPN_BLK - 1) / TPN_BLK;  // one wave per node

    // layer 1: hA = x @ W1 ; hB = relu(agg(hA) + b1)
    tpn_gemm<<<wgrid, TPN_BLK, 0, stream>>>(x, W1, hA, N, IN);
    tpn_agg<false><<<wgrid, TPN_BLK, 0, stream>>>(packed, off, cnt, hA, b1, pw, pb, hB, N);

    // layer 2: hA = hB @ W2 ; hB = score-gated relu(agg(hA) + b2)
    tpn_gemm<<<wgrid, TPN_BLK, 0, stream>>>(hB, W2, hA, N, 64);
    tpn_agg<true><<<wgrid, TPN_BLK, 0, stream>>>(packed, off, cnt, hA, b2, pw, pb, hB, N);

    // pooling + MLP head
    tpn_pool<<<G, TPN_BLK, 0, stream>>>(hB, bat, N, Gf);
    tpn_mlp<<<(G * 64 + TPN_BLK - 1) / TPN_BLK, TPN_BLK, 0, stream>>>(Gf, lw1, lb1, lw2, lb2, out, G, C);
}

// Round 2
// 855.730 us; speedup vs baseline: 1.2063x; 1.2063x over previous
//
#include <hip/hip_runtime.h>
#include <math.h>

// ---------------------------------------------------------------------------
// TopoPoolNet: GCN(128->64) -> GCN(64->64) -> sigmoid score gate ->
//              per-graph max||mean pool -> MLP(128->64->2)
//
// Round-1 redesign: the CSR build was dominated by far-atomic RMW traffic
// (every device atomic = 32B memory-side RMW; rocprof WRITE_SIZE showed
// 6.4M x 32B = 204.8MB for tpn_count alone). Now: ONE atomic per edge,
// scattering directly into fixed-capacity per-node buckets. deg/dis/norm
// derived atomics-free from the buckets.
// ---------------------------------------------------------------------------

#define TPN_BLK 256

// ---- single-pass bucket scatter: bucket[c*CAP + cur[c]++] = {row, w} -------
__global__ void tpn_scatter(const int* __restrict__ ei, const float* __restrict__ ew,
                            int* __restrict__ cur, uint2* __restrict__ bucket,
                            int E, int CAP) {
    int e = blockIdx.x * blockDim.x + threadIdx.x;
    if (e >= E) return;
    int r = ei[e], c = ei[E + e];
    float w = ew[e];
    int p = atomicAdd(&cur[c], 1);
    if (p < CAP)  // clamp insurance; CAP chosen >> max expected in-degree
        bucket[(size_t)c * CAP + p] = make_uint2((unsigned)r, __float_as_uint(w));
}

// ---- per-node weighted degree -> dis = rsqrt(deg) (wave per node) ----------
__global__ void tpn_degdis(const uint2* __restrict__ bucket, const int* __restrict__ cur,
                           float* __restrict__ dis, int N, int CAP) {
    int wid = (blockIdx.x * blockDim.x + threadIdx.x) >> 6;
    int lane = threadIdx.x & 63;
    if (wid >= N) return;
    int n = min(cur[wid], CAP);
    const uint2* b = bucket + (size_t)wid * CAP;
    float s = 0.0f;
    for (int j = lane; j < n; j += 64) s += __uint_as_float(b[j].y);
    #pragma unroll
    for (int m = 32; m > 0; m >>= 1) s += __shfl_xor(s, m);
    if (lane == 0) dis[wid] = (s > 0.0f) ? rsqrtf(fmaxf(s, 1e-12f)) : 0.0f;
}

// ---- rewrite bucket weights in place: w -> dis[row]*w*dis[col] -------------
__global__ void tpn_norm(uint2* __restrict__ bucket, const int* __restrict__ cur,
                         const float* __restrict__ dis, int N, int CAP) {
    int wid = (blockIdx.x * blockDim.x + threadIdx.x) >> 6;
    int lane = threadIdx.x & 63;
    if (wid >= N) return;
    int n = min(cur[wid], CAP);
    float dc = dis[wid];
    uint2* b = bucket + (size_t)wid * CAP;
    for (int j = lane; j < n; j += 64) {
        uint2 p = b[j];
        float nv = dis[p.x] * __uint_as_float(p.y) * dc;
        b[j] = make_uint2(p.x, __float_as_uint(nv));
    }
}

// ---- dense GEMM: Y[n, f] = sum_k X[n,k] * W[k,f];  one wave/node, lane=f ---
__global__ void tpn_gemm(const float* __restrict__ X, const float* __restrict__ W,
                         float* __restrict__ Y, int N, int K) {
    int wid = (blockIdx.x * blockDim.x + threadIdx.x) >> 6;
    int lane = threadIdx.x & 63;
    if (wid >= N) return;
    const float* xr = X + (size_t)wid * K;
    float acc = 0.0f;
    for (int k = 0; k < K; k += 4) {
        float4 xv = *reinterpret_cast<const float4*>(xr + k);
        acc = fmaf(xv.x, W[(k + 0) * 64 + lane], acc);
        acc = fmaf(xv.y, W[(k + 1) * 64 + lane], acc);
        acc = fmaf(xv.z, W[(k + 2) * 64 + lane], acc);
        acc = fmaf(xv.w, W[(k + 3) * 64 + lane], acc);
    }
    Y[(size_t)wid * 64 + lane] = acc;
}

// ---- aggregate: Hout[n,:] = relu(sum_{e in in(n)} norm_e * Hin[row_e,:] + b)
//      optionally fused sigmoid score gate (layer 2) ------------------------
template <bool FUSE_SCORE>
__global__ void tpn_agg(const uint2* __restrict__ bucket, const int* __restrict__ cur,
                        const float* __restrict__ Hin, const float* __restrict__ bias,
                        const float* __restrict__ pw, const float* __restrict__ pb,
                        float* __restrict__ Hout, int N, int CAP) {
    int wid = (blockIdx.x * blockDim.x + threadIdx.x) >> 6;
    int lane = threadIdx.x & 63;
    if (wid >= N) return;
    int n = min(cur[wid], CAP);
    const uint2* b = bucket + (size_t)wid * CAP;
    float acc = 0.0f;
    int j = 0;
    for (; j + 3 < n; j += 4) {
        uint2 p0 = b[j + 0];
        uint2 p1 = b[j + 1];
        uint2 p2 = b[j + 2];
        uint2 p3 = b[j + 3];
        acc = fmaf(__uint_as_float(p0.y), Hin[(size_t)p0.x * 64 + lane], acc);
        acc = fmaf(__uint_as_float(p1.y), Hin[(size_t)p1.x * 64 + lane], acc);
        acc = fmaf(__uint_as_float(p2.y), Hin[(size_t)p2.x * 64 + lane], acc);
        acc = fmaf(__uint_as_float(p3.y), Hin[(size_t)p3.x * 64 + lane], acc);
    }
    for (; j < n; ++j) {
        uint2 p = b[j];
        acc = fmaf(__uint_as_float(p.y), Hin[(size_t)p.x * 64 + lane], acc);
    }
    float h = fmaxf(acc + bias[lane], 0.0f);
    if (FUSE_SCORE) {
        float t = h * pw[lane];
        #pragma unroll
        for (int m = 32; m > 0; m >>= 1) t += __shfl_xor(t, m);
        float s = 1.0f / (1.0f + expf(-(t + pb[0])));
        h *= s;
    }
    Hout[(size_t)wid * 64 + lane] = h;
}

// ---- per-graph max || mean pooling (batch sorted) --------------------------
__global__ void tpn_pool(const float* __restrict__ Hs, const int* __restrict__ batch,
                         int N, float* __restrict__ Gf) {
    int g = blockIdx.x;
    int s, e;
    {
        int lo = 0, hi = N;
        while (lo < hi) { int mid = (lo + hi) >> 1; if (batch[mid] < g) lo = mid + 1; else hi = mid; }
        s = lo;
        lo = 0; hi = N;
        while (lo < hi) { int mid = (lo + hi) >> 1; if (batch[mid] < g + 1) lo = mid + 1; else hi = mid; }
        e = lo;
    }
    int lane = threadIdx.x & 63;
    int w = threadIdx.x >> 6;  // 0..3
    float mx = -3.4e38f, sm = 0.0f;
    for (int i = s + w; i < e; i += 4) {
        float v = Hs[(size_t)i * 64 + lane];
        mx = fmaxf(mx, v);
        sm += v;
    }
    __shared__ float shm[4][64], shs[4][64];
    shm[w][lane] = mx; shs[w][lane] = sm;
    __syncthreads();
    if (w == 0) {
        mx = fmaxf(fmaxf(shm[0][lane], shm[1][lane]), fmaxf(shm[2][lane], shm[3][lane]));
        sm = shs[0][lane] + shs[1][lane] + shs[2][lane] + shs[3][lane];
        float c = (float)(e - s);
        float inv = 1.0f / fmaxf(c, 1.0f);
        Gf[g * 128 + lane]      = mx;
        Gf[g * 128 + 64 + lane] = sm * inv;
    }
}

// ---- final MLP: out = relu(G @ lw1 + lb1) @ lw2 + lb2 ----------------------
__global__ void tpn_mlp(const float* __restrict__ Gf, const float* __restrict__ lw1,
                        const float* __restrict__ lb1, const float* __restrict__ lw2,
                        const float* __restrict__ lb2, float* __restrict__ out,
                        int G, int C) {
    int wid = (blockIdx.x * blockDim.x + threadIdx.x) >> 6;
    int lane = threadIdx.x & 63;
    if (wid >= G) return;
    const float* gr = Gf + (size_t)wid * 128;
    float acc = lb1[lane];
    for (int k = 0; k < 128; k += 4) {
        float4 gv = *reinterpret_cast<const float4*>(gr + k);
        acc = fmaf(gv.x, lw1[(k + 0) * 64 + lane], acc);
        acc = fmaf(gv.y, lw1[(k + 1) * 64 + lane], acc);
        acc = fmaf(gv.z, lw1[(k + 2) * 64 + lane], acc);
        acc = fmaf(gv.w, lw1[(k + 3) * 64 + lane], acc);
    }
    float t = fmaxf(acc, 0.0f);
    for (int c = 0; c < C; ++c) {
        float v = t * lw2[lane * C + c];
        #pragma unroll
        for (int m = 32; m > 0; m >>= 1) v += __shfl_xor(v, m);
        if (lane == 0) out[wid * C + c] = v + lb2[c];
    }
}

// ---------------------------------------------------------------------------
extern "C" void kernel_launch(void* const* d_in, const int* in_sizes, int n_in,
                              void* d_out, int out_size, void* d_ws, size_t ws_size,
                              hipStream_t stream) {
    const float* x   = (const float*)d_in[0];
    const int*   ei  = (const int*)  d_in[1];
    const float* ew  = (const float*)d_in[2];
    const int*   bat = (const int*)  d_in[3];
    const float* W1  = (const float*)d_in[5];
    const float* b1  = (const float*)d_in[6];
    const float* W2  = (const float*)d_in[7];
    const float* b2  = (const float*)d_in[8];
    const float* pw  = (const float*)d_in[9];
    const float* pb  = (const float*)d_in[10];
    const float* lw1 = (const float*)d_in[11];
    const float* lb1 = (const float*)d_in[12];
    const float* lw2 = (const float*)d_in[13];
    const float* lb2 = (const float*)d_in[14];
    float* out = (float*)d_out;

    const int N  = in_sizes[3];
    const int E  = in_sizes[2];
    const int IN = in_sizes[0] / N;   // 128
    const int C  = in_sizes[14];      // 2
    const int G  = out_size / C;      // 128

    // ---- workspace layout (bucket last so CAP can adapt to ws_size) ----
    char* ws = (char*)d_ws;
    size_t o = 0;
    auto alloc = [&](size_t bytes) { void* p = ws + o; o = (o + bytes + 255) & ~(size_t)255; return p; };
    int*   cur = (int*)  alloc((size_t)N * 4);
    float* dis = (float*)alloc((size_t)N * 4);
    float* hA  = (float*)alloc((size_t)N * 64 * 4);
    float* hB  = (float*)alloc((size_t)N * 64 * 4);
    float* Gf  = (float*)alloc((size_t)G * 128 * 4);

    int CAP = 80;  // P(max in-degree >= 80) ~ 1e-8 for Poisson(32) over 100k nodes
    {
        size_t avail = (ws_size > o) ? (ws_size - o) : 0;
        size_t fit = avail / ((size_t)N * 8);
        if (fit < (size_t)CAP) CAP = (int)fit;  // degrade gracefully, never OOB
    }
    uint2* bucket = (uint2*)alloc((size_t)N * CAP * 8);
    (void)n_in;

    hipMemsetAsync(cur, 0, (size_t)N * 4, stream);

    const int eb    = (E + TPN_BLK - 1) / TPN_BLK;
    const int wgrid = (N * 64 + TPN_BLK - 1) / TPN_BLK;  // one wave per node

    // CSR-by-destination build: one far atomic per edge, everything else free
    tpn_scatter<<<eb, TPN_BLK, 0, stream>>>(ei, ew, cur, bucket, E, CAP);
    tpn_degdis<<<wgrid, TPN_BLK, 0, stream>>>(bucket, cur, dis, N, CAP);
    tpn_norm<<<wgrid, TPN_BLK, 0, stream>>>(bucket, cur, dis, N, CAP);

    // layer 1: hA = x @ W1 ; hB = relu(agg(hA) + b1)
    tpn_gemm<<<wgrid, TPN_BLK, 0, stream>>>(x, W1, hA, N, IN);
    tpn_agg<false><<<wgrid, TPN_BLK, 0, stream>>>(bucket, cur, hA, b1, pw, pb, hB, N, CAP);

    // layer 2: hA = hB @ W2 ; hB = score-gated relu(agg(hA) + b2)
    tpn_gemm<<<wgrid, TPN_BLK, 0, stream>>>(hB, W2, hA, N, 64);
    tpn_agg<true><<<wgrid, TPN_BLK, 0, stream>>>(bucket, cur, hA, b2, pw, pb, hB, N, CAP);

    // pooling + MLP head
    tpn_pool<<<G, TPN_BLK, 0, stream>>>(hB, bat, N, Gf);
    tpn_mlp<<<(G * 64 + TPN_BLK - 1) / TPN_BLK, TPN_BLK, 0, stream>>>(Gf, lw1, lb1, lw2, lb2, out, G, C);
}

// Round 3
// 693.112 us; speedup vs baseline: 1.4893x; 1.2346x over previous
//
#include <hip/hip_runtime.h>
#include <math.h>

// ---------------------------------------------------------------------------
// TopoPoolNet: GCN(128->64) -> GCN(64->64) -> sigmoid score gate ->
//              per-graph max||mean pool -> MLP(128->64->2)
//
// Round-2 redesign: the single-pass bucket scatter was RMW-bound (3.2M far
// atomics + 3.2M random 8B stores = ~200MB HBM write for 25.6MB payload).
// Now a two-level multisplit: (1) bin edges by col>>8 with per-block LDS
// histograms (one global atomic per block*bin), (2) one block per bin builds
// a compact packed CSR + dis[] entirely in LDS/L2-local space.
// Assumes N <= 131072 (row packs in 17 bits) -- true for this problem.
// ---------------------------------------------------------------------------

#define TPN_BLK 256
#define P1_EPT  16                 // edges per thread in bin pass
#define P1_CHUNK (TPN_BLK * P1_EPT)  // 4096 edges per block
#define NB_MAX  512
#define BCAP    12288              // per-bin capacity (mean ~8184, +45 sigma)

// ---- pass 1: bin edges by destination high bits ----------------------------
__global__ void tpn_bin(const int* __restrict__ ei, const float* __restrict__ ew,
                        int* __restrict__ binCur, uint2* __restrict__ binned,
                        int E, int NB) {
    __shared__ int hist[NB_MAX];
    __shared__ int rank[NB_MAX];
    int tid = threadIdx.x;
    for (int b = tid; b < NB; b += TPN_BLK) { hist[b] = 0; rank[b] = 0; }
    __syncthreads();

    int base = blockIdx.x * P1_CHUNK;
    uint2 ed[P1_EPT];
    int   bn[P1_EPT];
    #pragma unroll
    for (int j = 0; j < P1_EPT; ++j) {
        int e = base + tid + j * TPN_BLK;
        bn[j] = -1;
        if (e < E) {
            int r = ei[e], c = ei[E + e];
            float w = ew[e];
            int b = c >> 8;
            bn[j] = b;
            ed[j] = make_uint2((unsigned)r | ((unsigned)(c & 255) << 17),
                               __float_as_uint(w));
            atomicAdd(&hist[b], 1);
        }
    }
    __syncthreads();
    // reserve global space per bin; hist[b] becomes this block's global base
    for (int b = tid; b < NB; b += TPN_BLK) {
        int h = hist[b];
        hist[b] = (h > 0) ? atomicAdd(&binCur[b], h) : 0;
    }
    __syncthreads();
    #pragma unroll
    for (int j = 0; j < P1_EPT; ++j) {
        if (bn[j] >= 0) {
            int p = hist[bn[j]] + atomicAdd(&rank[bn[j]], 1);
            if (p < BCAP) binned[(size_t)bn[j] * BCAP + p] = ed[j];
        }
    }
}

// ---- exclusive scan of bin counts (single block) ---------------------------
__global__ void tpn_binscan(const int* __restrict__ binCur, int* __restrict__ binOff,
                            int NB) {
    __shared__ int sh[NB_MAX];
    int t = threadIdx.x;
    int v = (t < NB) ? min(binCur[t], BCAP) : 0;
    sh[t] = v;
    __syncthreads();
    for (int st = 1; st < NB_MAX; st <<= 1) {
        int u = (t >= st) ? sh[t - st] : 0;
        __syncthreads();
        sh[t] += u;
        __syncthreads();
    }
    if (t < NB) binOff[t] = sh[t] - v;
}

// ---- pass 2: per-bin packed CSR build + dis ------------------------------
__global__ void tpn_build(const uint2* __restrict__ binned, const int* __restrict__ binCur,
                          const int* __restrict__ binOff, uint2* __restrict__ packed,
                          int* __restrict__ off, int* __restrict__ cnt,
                          float* __restrict__ dis, int N) {
    __shared__ int   lcnt[256];
    __shared__ int   loff[256];
    __shared__ int   lrank[256];
    __shared__ int   lincl[256];
    __shared__ float ldeg[256];
    int b = blockIdx.x, tid = threadIdx.x;
    int m = min(binCur[b], BCAP);
    const uint2* src = binned + (size_t)b * BCAP;
    lcnt[tid] = 0; lrank[tid] = 0; ldeg[tid] = 0.0f;
    __syncthreads();
    for (int i = tid; i < m; i += 256) {
        uint2 u = src[i];
        int ln = u.x >> 17;
        atomicAdd(&lcnt[ln], 1);
        atomicAdd(&ldeg[ln], __uint_as_float(u.y));
    }
    __syncthreads();
    lincl[tid] = lcnt[tid];
    __syncthreads();
    for (int st = 1; st < 256; st <<= 1) {
        int u = (tid >= st) ? lincl[tid - st] : 0;
        __syncthreads();
        lincl[tid] += u;
        __syncthreads();
    }
    int excl = lincl[tid] - lcnt[tid];
    loff[tid] = excl;
    int node = (b << 8) + tid;
    if (node < N) {
        off[node] = binOff[b] + excl;
        cnt[node] = lcnt[tid];
        float s = ldeg[tid];
        dis[node] = (s > 0.0f) ? rsqrtf(fmaxf(s, 1e-12f)) : 0.0f;
    }
    __syncthreads();
    int gbase = binOff[b];
    for (int i = tid; i < m; i += 256) {
        uint2 u = src[i];
        int ln = u.x >> 17;
        int rk = atomicAdd(&lrank[ln], 1);
        packed[gbase + loff[ln] + rk] = make_uint2(u.x & 0x1FFFF, u.y);
    }
}

// ---- edge-parallel: w *= dis[row]  (dis[col] folded into agg epilogue) -----
__global__ void tpn_norm(uint2* __restrict__ packed, const float* __restrict__ dis,
                         int E) {
    int i = blockIdx.x * blockDim.x + threadIdx.x;
    if (i >= E) return;
    uint2 p = packed[i];
    p.y = __float_as_uint(dis[p.x] * __uint_as_float(p.y));
    packed[i] = p;
}

// ---- dense GEMM: Y[n, f] = sum_k X[n,k] * W[k,f];  one wave/node, lane=f ---
__global__ void tpn_gemm(const float* __restrict__ X, const float* __restrict__ W,
                         float* __restrict__ Y, int N, int K) {
    int wid = (blockIdx.x * blockDim.x + threadIdx.x) >> 6;
    int lane = threadIdx.x & 63;
    if (wid >= N) return;
    const float* xr = X + (size_t)wid * K;
    float acc = 0.0f;
    for (int k = 0; k < K; k += 4) {
        float4 xv = *reinterpret_cast<const float4*>(xr + k);
        acc = fmaf(xv.x, W[(k + 0) * 64 + lane], acc);
        acc = fmaf(xv.y, W[(k + 1) * 64 + lane], acc);
        acc = fmaf(xv.z, W[(k + 2) * 64 + lane], acc);
        acc = fmaf(xv.w, W[(k + 3) * 64 + lane], acc);
    }
    Y[(size_t)wid * 64 + lane] = acc;
}

// ---- aggregate: Hout[n,:] = relu(dis[n]*sum_e w'_e*Hin[row_e,:] + b) -------
template <bool FUSE_SCORE>
__global__ void tpn_agg(const uint2* __restrict__ packed, const int* __restrict__ off,
                        const int* __restrict__ cnt, const float* __restrict__ dis,
                        const float* __restrict__ Hin, const float* __restrict__ bias,
                        const float* __restrict__ pw, const float* __restrict__ pb,
                        float* __restrict__ Hout, int N) {
    int wid = (blockIdx.x * blockDim.x + threadIdx.x) >> 6;
    int lane = threadIdx.x & 63;
    if (wid >= N) return;
    int start = off[wid], n = cnt[wid];
    const uint2* b = packed + start;
    float acc = 0.0f;
    int j = 0;
    for (; j + 3 < n; j += 4) {
        uint2 p0 = b[j + 0];
        uint2 p1 = b[j + 1];
        uint2 p2 = b[j + 2];
        uint2 p3 = b[j + 3];
        acc = fmaf(__uint_as_float(p0.y), Hin[(size_t)p0.x * 64 + lane], acc);
        acc = fmaf(__uint_as_float(p1.y), Hin[(size_t)p1.x * 64 + lane], acc);
        acc = fmaf(__uint_as_float(p2.y), Hin[(size_t)p2.x * 64 + lane], acc);
        acc = fmaf(__uint_as_float(p3.y), Hin[(size_t)p3.x * 64 + lane], acc);
    }
    for (; j < n; ++j) {
        uint2 p = b[j];
        acc = fmaf(__uint_as_float(p.y), Hin[(size_t)p.x * 64 + lane], acc);
    }
    float h = fmaxf(acc * dis[wid] + bias[lane], 0.0f);
    if (FUSE_SCORE) {
        float t = h * pw[lane];
        #pragma unroll
        for (int m = 32; m > 0; m >>= 1) t += __shfl_xor(t, m);
        float s = 1.0f / (1.0f + expf(-(t + pb[0])));
        h *= s;
    }
    Hout[(size_t)wid * 64 + lane] = h;
}

// ---- per-graph max || mean pooling (batch sorted) --------------------------
__global__ void tpn_pool(const float* __restrict__ Hs, const int* __restrict__ batch,
                         int N, float* __restrict__ Gf) {
    int g = blockIdx.x;
    int s, e;
    {
        int lo = 0, hi = N;
        while (lo < hi) { int mid = (lo + hi) >> 1; if (batch[mid] < g) lo = mid + 1; else hi = mid; }
        s = lo;
        lo = 0; hi = N;
        while (lo < hi) { int mid = (lo + hi) >> 1; if (batch[mid] < g + 1) lo = mid + 1; else hi = mid; }
        e = lo;
    }
    int lane = threadIdx.x & 63;
    int w = threadIdx.x >> 6;  // 0..3
    float mx = -3.4e38f, sm = 0.0f;
    for (int i = s + w; i < e; i += 4) {
        float v = Hs[(size_t)i * 64 + lane];
        mx = fmaxf(mx, v);
        sm += v;
    }
    __shared__ float shm[4][64], shs[4][64];
    shm[w][lane] = mx; shs[w][lane] = sm;
    __syncthreads();
    if (w == 0) {
        mx = fmaxf(fmaxf(shm[0][lane], shm[1][lane]), fmaxf(shm[2][lane], shm[3][lane]));
        sm = shs[0][lane] + shs[1][lane] + shs[2][lane] + shs[3][lane];
        float c = (float)(e - s);
        float inv = 1.0f / fmaxf(c, 1.0f);
        Gf[g * 128 + lane]      = mx;
        Gf[g * 128 + 64 + lane] = sm * inv;
    }
}

// ---- final MLP: out = relu(G @ lw1 + lb1) @ lw2 + lb2 ----------------------
__global__ void tpn_mlp(const float* __restrict__ Gf, const float* __restrict__ lw1,
                        const float* __restrict__ lb1, const float* __restrict__ lw2,
                        const float* __restrict__ lb2, float* __restrict__ out,
                        int G, int C) {
    int wid = (blockIdx.x * blockDim.x + threadIdx.x) >> 6;
    int lane = threadIdx.x & 63;
    if (wid >= G) return;
    const float* gr = Gf + (size_t)wid * 128;
    float acc = lb1[lane];
    for (int k = 0; k < 128; k += 4) {
        float4 gv = *reinterpret_cast<const float4*>(gr + k);
        acc = fmaf(gv.x, lw1[(k + 0) * 64 + lane], acc);
        acc = fmaf(gv.y, lw1[(k + 1) * 64 + lane], acc);
        acc = fmaf(gv.z, lw1[(k + 2) * 64 + lane], acc);
        acc = fmaf(gv.w, lw1[(k + 3) * 64 + lane], acc);
    }
    float t = fmaxf(acc, 0.0f);
    for (int c = 0; c < C; ++c) {
        float v = t * lw2[lane * C + c];
        #pragma unroll
        for (int m = 32; m > 0; m >>= 1) v += __shfl_xor(v, m);
        if (lane == 0) out[wid * C + c] = v + lb2[c];
    }
}

// ---------------------------------------------------------------------------
extern "C" void kernel_launch(void* const* d_in, const int* in_sizes, int n_in,
                              void* d_out, int out_size, void* d_ws, size_t ws_size,
                              hipStream_t stream) {
    const float* x   = (const float*)d_in[0];
    const int*   ei  = (const int*)  d_in[1];
    const float* ew  = (const float*)d_in[2];
    const int*   bat = (const int*)  d_in[3];
    const float* W1  = (const float*)d_in[5];
    const float* b1  = (const float*)d_in[6];
    const float* W2  = (const float*)d_in[7];
    const float* b2  = (const float*)d_in[8];
    const float* pw  = (const float*)d_in[9];
    const float* pb  = (const float*)d_in[10];
    const float* lw1 = (const float*)d_in[11];
    const float* lb1 = (const float*)d_in[12];
    const float* lw2 = (const float*)d_in[13];
    const float* lb2 = (const float*)d_in[14];
    float* out = (float*)d_out;

    const int N  = in_sizes[3];
    const int E  = in_sizes[2];
    const int IN = in_sizes[0] / N;   // 128
    const int C  = in_sizes[14];      // 2
    const int G  = out_size / C;      // 128
    const int NB = (N + 255) >> 8;    // 391 bins of 256 nodes

    // ---- workspace layout ----
    char* ws = (char*)d_ws;
    size_t o = 0;
    auto alloc = [&](size_t bytes) { void* p = ws + o; o = (o + bytes + 255) & ~(size_t)255; return p; };
    int*   off    = (int*)  alloc((size_t)N * 4);
    int*   cnt    = (int*)  alloc((size_t)N * 4);
    float* dis    = (float*)alloc((size_t)N * 4);
    int*   binCur = (int*)  alloc((size_t)NB_MAX * 4);
    int*   binOff = (int*)  alloc((size_t)NB_MAX * 4);
    float* Gf     = (float*)alloc((size_t)G * 128 * 4);
    uint2* packed = (uint2*)alloc((size_t)E * 8);
    float* hA     = (float*)alloc((size_t)N * 64 * 4);
    float* hB     = (float*)alloc((size_t)N * 64 * 4);
    // binned is dead after tpn_build -> alias it over hA/hB (38.4MB <= 51.2MB)
    uint2* binned = (uint2*)hA;
    (void)n_in; (void)ws_size;

    hipMemsetAsync(binCur, 0, (size_t)NB_MAX * 4, stream);

    const int p1b   = (E + P1_CHUNK - 1) / P1_CHUNK;
    const int eb    = (E + TPN_BLK - 1) / TPN_BLK;
    const int wgrid = (N * 64 + TPN_BLK - 1) / TPN_BLK;  // one wave per node

    // CSR build: bin -> scan -> build -> norm
    tpn_bin<<<p1b, TPN_BLK, 0, stream>>>(ei, ew, binCur, binned, E, NB);
    tpn_binscan<<<1, NB_MAX, 0, stream>>>(binCur, binOff, NB);
    tpn_build<<<NB, 256, 0, stream>>>(binned, binCur, binOff, packed, off, cnt, dis, N);
    tpn_norm<<<eb, TPN_BLK, 0, stream>>>(packed, dis, E);

    // layer 1: hA = x @ W1 ; hB = relu(dis*agg(hA) + b1)
    tpn_gemm<<<wgrid, TPN_BLK, 0, stream>>>(x, W1, hA, N, IN);
    tpn_agg<false><<<wgrid, TPN_BLK, 0, stream>>>(packed, off, cnt, dis, hA, b1, pw, pb, hB, N);

    // layer 2: hA = hB @ W2 ; hB = score-gated relu(dis*agg(hA) + b2)
    tpn_gemm<<<wgrid, TPN_BLK, 0, stream>>>(hB, W2, hA, N, 64);
    tpn_agg<true><<<wgrid, TPN_BLK, 0, stream>>>(packed, off, cnt, dis, hA, b2, pw, pb, hB, N);

    // pooling + MLP head
    tpn_pool<<<G, TPN_BLK, 0, stream>>>(hB, bat, N, Gf);
    tpn_mlp<<<(G * 64 + TPN_BLK - 1) / TPN_BLK, TPN_BLK, 0, stream>>>(Gf, lw1, lb1, lw2, lb2, out, G, C);
}

// Round 4
// 472.261 us; speedup vs baseline: 2.1858x; 1.4676x over previous
//
#include <hip/hip_runtime.h>
#include <math.h>

// ---------------------------------------------------------------------------
// TopoPoolNet: GCN(128->64) -> GCN(64->64) -> sigmoid score gate ->
//              per-graph max||mean pool -> MLP(128->64->2)
//
// Round-3: the one-wave-per-node GEMM was latency-bound (single dependent
// acc chain, 19% VALUBusy, 7.8 TF). Replaced with LDS-tiled 64x64 block GEMM,
// 4x4 register tile per thread (16 independent FMA chains, 16 FMA : 5 LDS
// reads per k). CSR build (bin/scan/build/norm) and agg unchanged.
// ---------------------------------------------------------------------------

#define TPN_BLK 256
#define P1_EPT  16                 // edges per thread in bin pass
#define P1_CHUNK (TPN_BLK * P1_EPT)  // 4096 edges per block
#define NB_MAX  512
#define BCAP    12288              // per-bin capacity (mean ~8184)

// ---- pass 1: bin edges by destination high bits ----------------------------
__global__ void tpn_bin(const int* __restrict__ ei, const float* __restrict__ ew,
                        int* __restrict__ binCur, uint2* __restrict__ binned,
                        int E, int NB) {
    __shared__ int hist[NB_MAX];
    __shared__ int rank[NB_MAX];
    int tid = threadIdx.x;
    for (int b = tid; b < NB; b += TPN_BLK) { hist[b] = 0; rank[b] = 0; }
    __syncthreads();

    int base = blockIdx.x * P1_CHUNK;
    uint2 ed[P1_EPT];
    int   bn[P1_EPT];
    #pragma unroll
    for (int j = 0; j < P1_EPT; ++j) {
        int e = base + tid + j * TPN_BLK;
        bn[j] = -1;
        if (e < E) {
            int r = ei[e], c = ei[E + e];
            float w = ew[e];
            int b = c >> 8;
            bn[j] = b;
            ed[j] = make_uint2((unsigned)r | ((unsigned)(c & 255) << 17),
                               __float_as_uint(w));
            atomicAdd(&hist[b], 1);
        }
    }
    __syncthreads();
    for (int b = tid; b < NB; b += TPN_BLK) {
        int h = hist[b];
        hist[b] = (h > 0) ? atomicAdd(&binCur[b], h) : 0;
    }
    __syncthreads();
    #pragma unroll
    for (int j = 0; j < P1_EPT; ++j) {
        if (bn[j] >= 0) {
            int p = hist[bn[j]] + atomicAdd(&rank[bn[j]], 1);
            if (p < BCAP) binned[(size_t)bn[j] * BCAP + p] = ed[j];
        }
    }
}

// ---- exclusive scan of bin counts (single block) ---------------------------
__global__ void tpn_binscan(const int* __restrict__ binCur, int* __restrict__ binOff,
                            int NB) {
    __shared__ int sh[NB_MAX];
    int t = threadIdx.x;
    int v = (t < NB) ? min(binCur[t], BCAP) : 0;
    sh[t] = v;
    __syncthreads();
    for (int st = 1; st < NB_MAX; st <<= 1) {
        int u = (t >= st) ? sh[t - st] : 0;
        __syncthreads();
        sh[t] += u;
        __syncthreads();
    }
    if (t < NB) binOff[t] = sh[t] - v;
}

// ---- pass 2: per-bin packed CSR build + dis ------------------------------
__global__ void tpn_build(const uint2* __restrict__ binned, const int* __restrict__ binCur,
                          const int* __restrict__ binOff, uint2* __restrict__ packed,
                          int* __restrict__ off, int* __restrict__ cnt,
                          float* __restrict__ dis, int N) {
    __shared__ int   lcnt[256];
    __shared__ int   loff[256];
    __shared__ int   lrank[256];
    __shared__ int   lincl[256];
    __shared__ float ldeg[256];
    int b = blockIdx.x, tid = threadIdx.x;
    int m = min(binCur[b], BCAP);
    const uint2* src = binned + (size_t)b * BCAP;
    lcnt[tid] = 0; lrank[tid] = 0; ldeg[tid] = 0.0f;
    __syncthreads();
    for (int i = tid; i < m; i += 256) {
        uint2 u = src[i];
        int ln = u.x >> 17;
        atomicAdd(&lcnt[ln], 1);
        atomicAdd(&ldeg[ln], __uint_as_float(u.y));
    }
    __syncthreads();
    lincl[tid] = lcnt[tid];
    __syncthreads();
    for (int st = 1; st < 256; st <<= 1) {
        int u = (tid >= st) ? lincl[tid - st] : 0;
        __syncthreads();
        lincl[tid] += u;
        __syncthreads();
    }
    int excl = lincl[tid] - lcnt[tid];
    loff[tid] = excl;
    int node = (b << 8) + tid;
    if (node < N) {
        off[node] = binOff[b] + excl;
        cnt[node] = lcnt[tid];
        float s = ldeg[tid];
        dis[node] = (s > 0.0f) ? rsqrtf(fmaxf(s, 1e-12f)) : 0.0f;
    }
    __syncthreads();
    int gbase = binOff[b];
    for (int i = tid; i < m; i += 256) {
        uint2 u = src[i];
        int ln = u.x >> 17;
        int rk = atomicAdd(&lrank[ln], 1);
        packed[gbase + loff[ln] + rk] = make_uint2(u.x & 0x1FFFF, u.y);
    }
}

// ---- edge-parallel: w *= dis[row]  (dis[col] folded into agg epilogue) -----
__global__ void tpn_norm(uint2* __restrict__ packed, const float* __restrict__ dis,
                         int E) {
    int i = blockIdx.x * blockDim.x + threadIdx.x;
    if (i >= E) return;
    uint2 p = packed[i];
    p.y = __float_as_uint(dis[p.x] * __uint_as_float(p.y));
    packed[i] = p;
}

// ---- tiled GEMM: Y[n,f] = sum_k X[n,k]*W[k,f], 64x64 tile, 4x4 per thread --
// K must be a multiple of 64 (128 or 64 here).
__global__ __launch_bounds__(256, 4)
void tpn_gemm_t(const float* __restrict__ X, const float* __restrict__ W,
                float* __restrict__ Y, int N, int K) {
    __shared__ float sX[64][68];   // [n][k] chunk; stride 68 floats (17x16B, b128-aligned)
    __shared__ float sW[64][64];   // [k][f] chunk
    const int t  = threadIdx.x;
    const int r  = t >> 4;         // 0..15 (staging row / node-group)
    const int cc = t & 15;         // 0..15 (staging 4-float col group)
    const int fg = t & 15;         // feature group: f0 = 4*fg
    const int ng = t >> 4;         // node group:    n0 = 4*ng
    const int nb = blockIdx.x * 64;

    float acc[4][4] = {{0.f}};

    for (int kc = 0; kc < K; kc += 64) {
        __syncthreads();
        // stage X chunk [64n][64k] (clamped rows; coalesced float4)
        #pragma unroll
        for (int p = 0; p < 4; ++p) {
            int n = nb + r + p * 16;
            int ns = (n < N) ? n : (N - 1);
            float4 v = *reinterpret_cast<const float4*>(X + (size_t)ns * K + kc + 4 * cc);
            *reinterpret_cast<float4*>(&sX[r + p * 16][4 * cc]) = v;
        }
        // stage W chunk [64k][64f]
        #pragma unroll
        for (int p = 0; p < 4; ++p) {
            int k = kc + r + p * 16;
            float4 v = *reinterpret_cast<const float4*>(W + (size_t)k * 64 + 4 * cc);
            *reinterpret_cast<float4*>(&sW[r + p * 16][4 * cc]) = v;
        }
        __syncthreads();
        #pragma unroll 4
        for (int k = 0; k < 64; ++k) {
            float4 wv = *reinterpret_cast<const float4*>(&sW[k][4 * fg]);
            float x0 = sX[4 * ng + 0][k];
            float x1 = sX[4 * ng + 1][k];
            float x2 = sX[4 * ng + 2][k];
            float x3 = sX[4 * ng + 3][k];
            acc[0][0] = fmaf(x0, wv.x, acc[0][0]);
            acc[0][1] = fmaf(x0, wv.y, acc[0][1]);
            acc[0][2] = fmaf(x0, wv.z, acc[0][2]);
            acc[0][3] = fmaf(x0, wv.w, acc[0][3]);
            acc[1][0] = fmaf(x1, wv.x, acc[1][0]);
            acc[1][1] = fmaf(x1, wv.y, acc[1][1]);
            acc[1][2] = fmaf(x1, wv.z, acc[1][2]);
            acc[1][3] = fmaf(x1, wv.w, acc[1][3]);
            acc[2][0] = fmaf(x2, wv.x, acc[2][0]);
            acc[2][1] = fmaf(x2, wv.y, acc[2][1]);
            acc[2][2] = fmaf(x2, wv.z, acc[2][2]);
            acc[2][3] = fmaf(x2, wv.w, acc[2][3]);
            acc[3][0] = fmaf(x3, wv.x, acc[3][0]);
            acc[3][1] = fmaf(x3, wv.y, acc[3][1]);
            acc[3][2] = fmaf(x3, wv.z, acc[3][2]);
            acc[3][3] = fmaf(x3, wv.w, acc[3][3]);
        }
    }
    #pragma unroll
    for (int i = 0; i < 4; ++i) {
        int n = nb + 4 * ng + i;
        if (n < N) {
            float4 v = make_float4(acc[i][0], acc[i][1], acc[i][2], acc[i][3]);
            *reinterpret_cast<float4*>(Y + (size_t)n * 64 + 4 * fg) = v;
        }
    }
}

// ---- aggregate: Hout[n,:] = relu(dis[n]*sum_e w'_e*Hin[row_e,:] + b) -------
template <bool FUSE_SCORE>
__global__ void tpn_agg(const uint2* __restrict__ packed, const int* __restrict__ off,
                        const int* __restrict__ cnt, const float* __restrict__ dis,
                        const float* __restrict__ Hin, const float* __restrict__ bias,
                        const float* __restrict__ pw, const float* __restrict__ pb,
                        float* __restrict__ Hout, int N) {
    int wid = (blockIdx.x * blockDim.x + threadIdx.x) >> 6;
    int lane = threadIdx.x & 63;
    if (wid >= N) return;
    int start = off[wid], n = cnt[wid];
    const uint2* b = packed + start;
    float acc = 0.0f;
    int j = 0;
    for (; j + 3 < n; j += 4) {
        uint2 p0 = b[j + 0];
        uint2 p1 = b[j + 1];
        uint2 p2 = b[j + 2];
        uint2 p3 = b[j + 3];
        acc = fmaf(__uint_as_float(p0.y), Hin[(size_t)p0.x * 64 + lane], acc);
        acc = fmaf(__uint_as_float(p1.y), Hin[(size_t)p1.x * 64 + lane], acc);
        acc = fmaf(__uint_as_float(p2.y), Hin[(size_t)p2.x * 64 + lane], acc);
        acc = fmaf(__uint_as_float(p3.y), Hin[(size_t)p3.x * 64 + lane], acc);
    }
    for (; j < n; ++j) {
        uint2 p = b[j];
        acc = fmaf(__uint_as_float(p.y), Hin[(size_t)p.x * 64 + lane], acc);
    }
    float h = fmaxf(acc * dis[wid] + bias[lane], 0.0f);
    if (FUSE_SCORE) {
        float t = h * pw[lane];
        #pragma unroll
        for (int m = 32; m > 0; m >>= 1) t += __shfl_xor(t, m);
        float s = 1.0f / (1.0f + expf(-(t + pb[0])));
        h *= s;
    }
    Hout[(size_t)wid * 64 + lane] = h;
}

// ---- per-graph max || mean pooling (batch sorted) --------------------------
__global__ void tpn_pool(const float* __restrict__ Hs, const int* __restrict__ batch,
                         int N, float* __restrict__ Gf) {
    int g = blockIdx.x;
    int s, e;
    {
        int lo = 0, hi = N;
        while (lo < hi) { int mid = (lo + hi) >> 1; if (batch[mid] < g) lo = mid + 1; else hi = mid; }
        s = lo;
        lo = 0; hi = N;
        while (lo < hi) { int mid = (lo + hi) >> 1; if (batch[mid] < g + 1) lo = mid + 1; else hi = mid; }
        e = lo;
    }
    int lane = threadIdx.x & 63;
    int w = threadIdx.x >> 6;  // 0..3
    float mx = -3.4e38f, sm = 0.0f;
    for (int i = s + w; i < e; i += 4) {
        float v = Hs[(size_t)i * 64 + lane];
        mx = fmaxf(mx, v);
        sm += v;
    }
    __shared__ float shm[4][64], shs[4][64];
    shm[w][lane] = mx; shs[w][lane] = sm;
    __syncthreads();
    if (w == 0) {
        mx = fmaxf(fmaxf(shm[0][lane], shm[1][lane]), fmaxf(shm[2][lane], shm[3][lane]));
        sm = shs[0][lane] + shs[1][lane] + shs[2][lane] + shs[3][lane];
        float c = (float)(e - s);
        float inv = 1.0f / fmaxf(c, 1.0f);
        Gf[g * 128 + lane]      = mx;
        Gf[g * 128 + 64 + lane] = sm * inv;
    }
}

// ---- final MLP: out = relu(G @ lw1 + lb1) @ lw2 + lb2 ----------------------
__global__ void tpn_mlp(const float* __restrict__ Gf, const float* __restrict__ lw1,
                        const float* __restrict__ lb1, const float* __restrict__ lw2,
                        const float* __restrict__ lb2, float* __restrict__ out,
                        int G, int C) {
    int wid = (blockIdx.x * blockDim.x + threadIdx.x) >> 6;
    int lane = threadIdx.x & 63;
    if (wid >= G) return;
    const float* gr = Gf + (size_t)wid * 128;
    float acc = lb1[lane];
    for (int k = 0; k < 128; k += 4) {
        float4 gv = *reinterpret_cast<const float4*>(gr + k);
        acc = fmaf(gv.x, lw1[(k + 0) * 64 + lane], acc);
        acc = fmaf(gv.y, lw1[(k + 1) * 64 + lane], acc);
        acc = fmaf(gv.z, lw1[(k + 2) * 64 + lane], acc);
        acc = fmaf(gv.w, lw1[(k + 3) * 64 + lane], acc);
    }
    float t = fmaxf(acc, 0.0f);
    for (int c = 0; c < C; ++c) {
        float v = t * lw2[lane * C + c];
        #pragma unroll
        for (int m = 32; m > 0; m >>= 1) v += __shfl_xor(v, m);
        if (lane == 0) out[wid * C + c] = v + lb2[c];
    }
}

// ---------------------------------------------------------------------------
extern "C" void kernel_launch(void* const* d_in, const int* in_sizes, int n_in,
                              void* d_out, int out_size, void* d_ws, size_t ws_size,
                              hipStream_t stream) {
    const float* x   = (const float*)d_in[0];
    const int*   ei  = (const int*)  d_in[1];
    const float* ew  = (const float*)d_in[2];
    const int*   bat = (const int*)  d_in[3];
    const float* W1  = (const float*)d_in[5];
    const float* b1  = (const float*)d_in[6];
    const float* W2  = (const float*)d_in[7];
    const float* b2  = (const float*)d_in[8];
    const float* pw  = (const float*)d_in[9];
    const float* pb  = (const float*)d_in[10];
    const float* lw1 = (const float*)d_in[11];
    const float* lb1 = (const float*)d_in[12];
    const float* lw2 = (const float*)d_in[13];
    const float* lb2 = (const float*)d_in[14];
    float* out = (float*)d_out;

    const int N  = in_sizes[3];
    const int E  = in_sizes[2];
    const int IN = in_sizes[0] / N;   // 128
    const int C  = in_sizes[14];      // 2
    const int G  = out_size / C;      // 128
    const int NB = (N + 255) >> 8;    // bins of 256 nodes

    // ---- workspace layout ----
    char* ws = (char*)d_ws;
    size_t o = 0;
    auto alloc = [&](size_t bytes) { void* p = ws + o; o = (o + bytes + 255) & ~(size_t)255; return p; };
    int*   off    = (int*)  alloc((size_t)N * 4);
    int*   cnt    = (int*)  alloc((size_t)N * 4);
    float* dis    = (float*)alloc((size_t)N * 4);
    int*   binCur = (int*)  alloc((size_t)NB_MAX * 4);
    int*   binOff = (int*)  alloc((size_t)NB_MAX * 4);
    float* Gf     = (float*)alloc((size_t)G * 128 * 4);
    uint2* packed = (uint2*)alloc((size_t)E * 8);
    float* hA     = (float*)alloc((size_t)N * 64 * 4);
    float* hB     = (float*)alloc((size_t)N * 64 * 4);
    // binned is dead after tpn_build -> alias it over hA/hB (38.4MB <= 51.2MB)
    uint2* binned = (uint2*)hA;
    (void)n_in; (void)ws_size;

    hipMemsetAsync(binCur, 0, (size_t)NB_MAX * 4, stream);

    const int p1b   = (E + P1_CHUNK - 1) / P1_CHUNK;
    const int eb    = (E + TPN_BLK - 1) / TPN_BLK;
    const int wgrid = (N * 64 + TPN_BLK - 1) / TPN_BLK;  // one wave per node
    const int ggrid = (N + 63) / 64;                      // gemm tiles

    // CSR build: bin -> scan -> build -> norm
    tpn_bin<<<p1b, TPN_BLK, 0, stream>>>(ei, ew, binCur, binned, E, NB);
    tpn_binscan<<<1, NB_MAX, 0, stream>>>(binCur, binOff, NB);
    tpn_build<<<NB, 256, 0, stream>>>(binned, binCur, binOff, packed, off, cnt, dis, N);
    tpn_norm<<<eb, TPN_BLK, 0, stream>>>(packed, dis, E);

    // layer 1: hA = x @ W1 ; hB = relu(dis*agg(hA) + b1)
    tpn_gemm_t<<<ggrid, 256, 0, stream>>>(x, W1, hA, N, IN);
    tpn_agg<false><<<wgrid, TPN_BLK, 0, stream>>>(packed, off, cnt, dis, hA, b1, pw, pb, hB, N);

    // layer 2: hA = hB @ W2 ; hB = score-gated relu(dis*agg(hA) + b2)
    tpn_gemm_t<<<ggrid, 256, 0, stream>>>(hB, W2, hA, N, 64);
    tpn_agg<true><<<wgrid, TPN_BLK, 0, stream>>>(packed, off, cnt, dis, hA, b2, pw, pb, hB, N);

    // pooling + MLP head
    tpn_pool<<<G, TPN_BLK, 0, stream>>>(hB, bat, N, Gf);
    tpn_mlp<<<(G * 64 + TPN_BLK - 1) / TPN_BLK, TPN_BLK, 0, stream>>>(Gf, lw1, lb1, lw2, lb2, out, G, C);
}